// Round 8
// baseline (51774.756 us; speedup 1.0000x reference)
//
#include <hip/hip_runtime.h>
#include <math.h>

#define NB 256
#define NT 4096
#define NH 128

#define DWL_OFF (NB*NT)            // 1048576
#define OUT_OFF (NB*NT + NB*2)     // 1049088

// fast transcendentals: v_exp_f32 + v_rcp_f32 (~1e-6 rel err vs 2e-3 tolerance)
__device__ __forceinline__ float fexp2_(float x) { return __builtin_amdgcn_exp2f(x); }
__device__ __forceinline__ float frcp_(float x)  { return __builtin_amdgcn_rcpf(x); }
__device__ __forceinline__ float fsig_(float v)  { return frcp_(1.0f + fexp2_(v * -1.44269504f)); }
__device__ __forceinline__ float ftanh_(float v) { return 1.0f - 2.0f * frcp_(1.0f + fexp2_(v * 2.88539008f)); }

// wave64 sum: 4 VALU-DPP steps (16-lane row sums) + 2 cross-row shuffles
template <int CTRL>
__device__ __forceinline__ float dppadd_(float v) {
    return v + __int_as_float(__builtin_amdgcn_update_dpp(0, __float_as_int(v), CTRL, 0xF, 0xF, true));
}
__device__ __forceinline__ float wave_sum_(float v) {
    v = dppadd_<0xB1>(v);   // quad_perm xor1
    v = dppadd_<0x4E>(v);   // quad_perm xor2
    v = dppadd_<0x124>(v);  // row_ror:4
    v = dppadd_<0x128>(v);  // row_ror:8 -> 16-lane row sum in every lane
    v += __shfl_xor(v, 16);
    v += __shfl_xor(v, 32);
    return v;
}

// 1024 threads: row = tid>>1 (512 rows: 0-127 dnn_w1, 128-511 gru_w_hh r/z/n), half = tid&1.
// Each thread holds a 64-float half-row -> ~100 VGPRs total, fits the 128-reg cap at 16 waves.
// hi-half activation copies live at +80 floats (bank offset 16) so a wave's two broadcast
// addresses (even lanes lo, odd lanes hi) hit disjoint bank groups.
__launch_bounds__(1024, 1)
__global__ void drnn_fused(const float* __restrict__ x,
                           const float* __restrict__ W0in,
                           const float* __restrict__ h0,
                           const float* __restrict__ dnn_w0, const float* __restrict__ dnn_b0,
                           const float* __restrict__ dnn_w1, const float* __restrict__ dnn_b1,
                           const float* __restrict__ dnn_w2, const float* __restrict__ dnn_b2,
                           const float* __restrict__ gru_w_ih, const float* __restrict__ gru_w_hh,
                           const float* __restrict__ gru_b_ih, const float* __restrict__ gru_b_hh,
                           const float* __restrict__ fc_w, const float* __restrict__ scaling,
                           float* __restrict__ out)
{
    __shared__ float xb[NT * 3];                 // 48 KB staged x[b]
    __shared__ float ob_sig[NT];                 // 16 KB output buffer (sigmoid head)
    __shared__ __align__(16) float ob_W[NT * 2]; // 32 KB output buffer (W per step)
    __shared__ float sh_a0[144];                 // a0: lo [0..64), hi [80..144)
    __shared__ float sh_h[144];                  // h : lo [0..64), hi [80..144)
    __shared__ float sh_rg[NH];
    __shared__ float sh_zg[NH];
    __shared__ __align__(16) float sh_xtp[8];    // 4 D-wave xt partials (float2 each)
    __shared__ __align__(16) float sh_dwp[8];    // 4 n-wave dW partials (float2 each)

    const int tid  = threadIdx.x;
    const int lane = tid & 63;
    const int wv   = tid >> 6;
    const int row  = tid >> 1;
    const int half = tid & 1;
    const int b    = blockIdx.x;
    const bool isD = (row < NH);

    // ---- stage x[b] (3072 float4, coalesced) ----
    {
        const float4* src = (const float4*)(x + (size_t)b * (NT * 3));
        float4* dst = (float4*)xb;
        #pragma unroll
        for (int i = 0; i < 3; ++i) dst[tid + i * 1024] = src[tid + i * 1024];
    }

    // ---- 64-float half-row in arch VGPRs ----
    float wreg[64];
    {
        const float* sw = isD ? (dnn_w1 + (size_t)row * NH + half * 64)
                              : (gru_w_hh + (size_t)(row - NH) * NH + half * 64);
        #pragma unroll
        for (int k = 0; k < 64; k += 4) {
            float4 v = *(const float4*)(sw + k);
            wreg[k] = v.x; wreg[k+1] = v.y; wreg[k+2] = v.z; wreg[k+3] = v.w;
        }
    }

    // ---- per-role small weights ----
    float w00_0=0,w00_1=0,w00_2=0,w00_3=0, w01_0=0,w01_1=0,w01_2=0,w01_3=0;
    float b0a=0, b0b=0, b1r=0, w20=0, w21=0, sc0=0, sc1=0, Wr0=0, Wr1=0;
    float wih0=0, wih1=0, bih=0, bhh=0, b2_0=0, b2_1=0, fc0=0, fc1=0, hreg=0;
    int gate = -1, u = 0;
    if (isD) {
        // each D wave redundantly computes ALL 128 a0 (units lane, lane+64)
        w00_0 = dnn_w0[lane*4+0]; w00_1 = dnn_w0[lane*4+1];
        w00_2 = dnn_w0[lane*4+2]; w00_3 = dnn_w0[lane*4+3];
        w01_0 = dnn_w0[(lane+64)*4+0]; w01_1 = dnn_w0[(lane+64)*4+1];
        w01_2 = dnn_w0[(lane+64)*4+2]; w01_3 = dnn_w0[(lane+64)*4+3];
        b0a = dnn_b0[lane]; b0b = dnn_b0[lane+64];
        b1r = dnn_b1[row];
        w20 = dnn_w2[row]; w21 = dnn_w2[NH + row];
        sc0 = scaling[0]; sc1 = scaling[1];
        Wr0 = W0in[2*b]; Wr1 = W0in[2*b+1];
    } else {
        const int grow = row - NH;          // 0..383
        gate = grow >> 7;                   // 0=r 1=z 2=n
        u = grow & 127;
        wih0 = gru_w_ih[grow*2+0]; wih1 = gru_w_ih[grow*2+1];
        bih = gru_b_ih[grow]; bhh = gru_b_hh[grow];
        b2_0 = dnn_b2[0]; b2_1 = dnn_b2[1];
        if (gate == 2) {
            fc0 = fc_w[u]; fc1 = fc_w[NH + u];
            hreg = h0[(size_t)b * NH + u];
            if (!half) { if (u < 64) sh_h[u] = hreg; else sh_h[80 + u - 64] = hreg; }
        }
    }
    __syncthreads();

    for (int t = 0; t < NT; ++t) {
        float gh = 0.f, gin = 0.f;

        // ---------------- P1: D {W-finalize(t-1), a0, a1 half-dot, xt partial} || G {gh half-dot} ----
        if (isD) {
            if (t > 0) {
                const float4 q0 = *(const float4*)sh_dwp;       // uniform broadcast
                const float4 q1 = *(const float4*)(sh_dwp + 4);
                Wr0 += (q0.x + q0.z + q1.x + q1.z) * sc0;       // identical in all D threads
                Wr1 += (q0.y + q0.w + q1.y + q1.w) * sc1;
                if (tid == 0) {
                    const int tp = t - 1;
                    ob_sig[tp] = fsig_(fmaf(Wr0, xb[tp * 3], Wr1));
                    *(float2*)(ob_W + tp * 2) = make_float2(Wr0, Wr1);
                }
            }
            const float i2 = xb[t*3+1], i3 = xb[t*3+2];
            const float a0a = fmaf(w00_0, Wr0, fmaf(w00_1, Wr1, fmaf(w00_2, i2, fmaf(w00_3, i3, b0a))));
            const float a0b = fmaf(w01_0, Wr0, fmaf(w01_1, Wr1, fmaf(w01_2, i2, fmaf(w01_3, i3, b0b))));
            // every D wave writes all 128 a0 -> only same-wave ordering needed; redundant
            // writes across the 4 D waves are bitwise identical (benign race)
            sh_a0[lane]      = fmaxf(a0a, 0.f);
            sh_a0[80 + lane] = fmaxf(a0b, 0.f);
            asm volatile("s_waitcnt lgkmcnt(0)" ::: "memory");
            const float* base = half ? (sh_a0 + 80) : sh_a0;
            float ac0=0.f, ac1=0.f, ac2=0.f, ac3=0.f;
            #pragma unroll
            for (int k = 0; k < 64; k += 4) {
                const float4 v = *(const float4*)(base + k);    // 2 bank-disjoint broadcasts
                ac0 = fmaf(wreg[k+0], v.x, ac0); ac1 = fmaf(wreg[k+1], v.y, ac1);
                ac2 = fmaf(wreg[k+2], v.z, ac2); ac3 = fmaf(wreg[k+3], v.w, ac3);
            }
            float s = (ac0 + ac1) + (ac2 + ac3);
            s += __shfl_xor(s, 1);                              // combine the two halves
            const float a1 = fmaxf(s + b1r, 0.f);
            float c0 = half ? 0.f : w20 * a1;                   // count each row once
            float c1 = half ? 0.f : w21 * a1;
            c0 = wave_sum_(c0); c1 = wave_sum_(c1);
            if (lane == 0) *(float2*)(sh_xtp + wv * 2) = make_float2(c0, c1);
        } else {
            const float* base = half ? (sh_h + 80) : sh_h;
            float ac0=0.f, ac1=0.f, ac2=0.f, ac3=0.f;
            #pragma unroll
            for (int k = 0; k < 64; k += 4) {
                const float4 v = *(const float4*)(base + k);
                ac0 = fmaf(wreg[k+0], v.x, ac0); ac1 = fmaf(wreg[k+1], v.y, ac1);
                ac2 = fmaf(wreg[k+2], v.z, ac2); ac3 = fmaf(wreg[k+3], v.w, ac3);
            }
            float s = (ac0 + ac1) + (ac2 + ac3);
            s += __shfl_xor(s, 1);
            gh = s + bhh;
        }
        __syncthreads();   // S1: xt partials ready; h reads done

        // ---------------- P2: G — sum xt partials, gi, r/z gates to LDS; n holds gin ---------
        if (!isD) {
            const float4 q0 = *(const float4*)sh_xtp;           // uniform broadcast
            const float4 q1 = *(const float4*)(sh_xtp + 4);
            const float xt0 = q0.x + q0.z + q1.x + q1.z + b2_0;
            const float xt1 = q0.y + q0.w + q1.y + q1.w + b2_1;
            const float gi = fmaf(wih0, xt0, fmaf(wih1, xt1, bih));
            if (gate == 0)      { if (!half) sh_rg[u] = fsig_(gi + gh); }
            else if (gate == 1) { if (!half) sh_zg[u] = fsig_(gi + gh); }
            else                gin = gi;
        }
        __syncthreads();   // S2: gates ready

        // ---------------- P3: n threads — h' (thread-local), dW partials ---------------------
        if (gate == 2) {
            const float rg = sh_rg[u], zg = sh_zg[u];           // 2 lanes/word broadcast
            const float ng = ftanh_(fmaf(rg, gh, gin));
            const float hn = fmaf(zg, hreg - ng, ng);           // (1-z)*n + z*h
            hreg = hn;
            if (!half) { if (u < 64) sh_h[u] = hn; else sh_h[80 + u - 64] = hn; }
            float p0 = half ? 0.f : fc0 * hn;
            float p1 = half ? 0.f : fc1 * hn;
            p0 = wave_sum_(p0); p1 = wave_sum_(p1);
            if (lane == 0) *(float2*)(sh_dwp + (wv - 12) * 2) = make_float2(p0, p1);
        }
        __syncthreads();   // S3: h', dW partials ready
    }

    // ---------------- epilogue: finalize t = NT-1, then coalesced flush ----------------
    if (tid == 0) {
        const float4 q0 = *(const float4*)sh_dwp;
        const float4 q1 = *(const float4*)(sh_dwp + 4);
        const float d0 = (q0.x + q0.z + q1.x + q1.z) * sc0;
        const float d1 = (q0.y + q0.w + q1.y + q1.w) * sc1;
        Wr0 += d0; Wr1 += d1;
        const int tp = NT - 1;
        ob_sig[tp] = fsig_(fmaf(Wr0, xb[tp * 3], Wr1));
        *(float2*)(ob_W + tp * 2) = make_float2(Wr0, Wr1);
        out[DWL_OFF + 2*b + 0] = d0;
        out[DWL_OFF + 2*b + 1] = d1;
    }
    __syncthreads();
    {
        float4* osig = (float4*)(out + (size_t)b * NT);
        osig[tid] = ((const float4*)ob_sig)[tid];               // 4096 floats
        float4* ow = (float4*)(out + OUT_OFF + (size_t)b * NT * 2);
        ow[tid]        = ((const float4*)ob_W)[tid];            // 8192 floats
        ow[tid + 1024] = ((const float4*)ob_W)[tid + 1024];
    }
}

extern "C" void kernel_launch(void* const* d_in, const int* in_sizes, int n_in,
                              void* d_out, int out_size, void* d_ws, size_t ws_size,
                              hipStream_t stream) {
    (void)in_sizes; (void)n_in; (void)out_size; (void)d_ws; (void)ws_size;
    const float* x        = (const float*)d_in[0];
    const float* W0in     = (const float*)d_in[1];
    const float* h0       = (const float*)d_in[2];
    const float* dnn_w0   = (const float*)d_in[3];
    const float* dnn_b0   = (const float*)d_in[4];
    const float* dnn_w1   = (const float*)d_in[5];
    const float* dnn_b1   = (const float*)d_in[6];
    const float* dnn_w2   = (const float*)d_in[7];
    const float* dnn_b2   = (const float*)d_in[8];
    const float* gru_w_ih = (const float*)d_in[9];
    const float* gru_w_hh = (const float*)d_in[10];
    const float* gru_b_ih = (const float*)d_in[11];
    const float* gru_b_hh = (const float*)d_in[12];
    const float* fc_w     = (const float*)d_in[13];
    const float* scaling  = (const float*)d_in[14];
    float* out = (float*)d_out;

    drnn_fused<<<NB, 1024, 0, stream>>>(x, W0in, h0, dnn_w0, dnn_b0, dnn_w1, dnn_b1,
                                        dnn_w2, dnn_b2, gru_w_ih, gru_w_hh, gru_b_ih,
                                        gru_b_hh, fc_w, scaling, out);
}